// Round 11
// baseline (856.298 us; speedup 1.0000x reference)
//
#include <hip/hip_runtime.h>
#include <hip/hip_bf16.h>

#define TT 512
#define DH 2048
#define FFD 768
#define NE 128
#define TOPK 8
#define CAP 512
#define SMAX 64

typedef __attribute__((ext_vector_type(4))) float f32x4;
typedef __attribute__((ext_vector_type(8))) short short8;

typedef __attribute__((address_space(3))) unsigned int lds_u32_t;
typedef __attribute__((address_space(1))) unsigned int glob_u32_t;

__device__ __forceinline__ short f2bf(float f) {
    __hip_bfloat16 h = __float2bfloat16(f);
    return *reinterpret_cast<short*>(&h);
}

// async DMA: 16B/lane, global -> LDS (per-lane global src, wave-uniform LDS dest + lane*16)
__device__ __forceinline__ void glds16(const float* g, float* l) {
    __builtin_amdgcn_global_load_lds((glob_u32_t*)g, (lds_u32_t*)l, 16, 0, 0);
}

template<int N>
__device__ __forceinline__ void vmwait() {
    asm volatile("s_waitcnt vmcnt(%0)" :: "i"(N) : "memory");
}

// ---------------- Init: zero cnt only ----------------
__global__ __launch_bounds__(128) void moe_init(int* __restrict__ cnt)
{
    cnt[threadIdx.x] = 0;
}

// ---------------- Router (also zeroes its token's output row) ----------------
__global__ __launch_bounds__(128) void moe_router(
    const float* __restrict__ x, const float* __restrict__ wg,
    int* __restrict__ cnt, int* __restrict__ tok_list, float* __restrict__ w_list,
    float* __restrict__ out)
{
    const int t = blockIdx.x;
    const int e = threadIdx.x;
    __shared__ float xs[DH];
    __shared__ float red[NE];
    __shared__ int   redi[NE];
    __shared__ float selw[TOPK];
    __shared__ int   seli[TOPK];

    float4* outrow = (float4*)(out + (size_t)t * DH);
    const float4 z4 = make_float4(0.f, 0.f, 0.f, 0.f);
    #pragma unroll
    for (int i = 0; i < 4; ++i) outrow[e + i * 128] = z4;

    for (int i = e; i < DH; i += 128) xs[i] = x[(size_t)t * DH + i];
    __syncthreads();

    float acc = 0.f;
    #pragma unroll 4
    for (int d = 0; d < DH; ++d)
        acc = fmaf(xs[d], wg[(size_t)d * NE + e], acc);

    red[e] = acc; __syncthreads();
    for (int s = 64; s > 0; s >>= 1) {
        if (e < s) red[e] = fmaxf(red[e], red[e + s]);
        __syncthreads();
    }
    const float mx = red[0];
    __syncthreads();

    float myp = __expf(acc - mx);

    for (int k = 0; k < TOPK; ++k) {
        red[e] = myp; redi[e] = e;
        __syncthreads();
        for (int s = 64; s > 0; s >>= 1) {
            if (e < s) {
                const float v2 = red[e + s]; const int i2 = redi[e + s];
                if (v2 > red[e] || (v2 == red[e] && i2 < redi[e])) { red[e] = v2; redi[e] = i2; }
            }
            __syncthreads();
        }
        if (e == 0) { selw[k] = red[0]; seli[k] = redi[0]; }
        __syncthreads();
        if (e == seli[k]) myp = -1.f;
        __syncthreads();
    }

    if (e == 0) {
        float s8 = 0.f;
        #pragma unroll
        for (int k = 0; k < TOPK; ++k) s8 += selw[k];
        const float inv = 1.f / s8;
        #pragma unroll
        for (int k = 0; k < TOPK; ++k) {
            const int ex = seli[k];
            const float wv = selw[k] * inv;
            const int pos = atomicAdd(&cnt[ex], 1);
            if (pos < CAP) {
                tok_list[ex * CAP + pos] = t * TOPK + k;
                w_list[ex * CAP + pos] = wv;
            }
        }
    }
}

// ---------------- Gather: xgb[e][slot][k] bf16, zero-padded to SMAX rows ----------------
__global__ __launch_bounds__(256) void moe_gather(
    const float* __restrict__ x, const int* __restrict__ cnt,
    const int* __restrict__ tok_list, short* __restrict__ xgb)
{
    const int e = blockIdx.x;
    int n = cnt[e]; if (n > SMAX) n = SMAX;
    const int k = threadIdx.x * 8;
    short* dste = xgb + (size_t)e * SMAX * DH;
    for (int s = 0; s < SMAX; ++s) {
        short8 o = {0, 0, 0, 0, 0, 0, 0, 0};
        if (s < n) {
            const float* xr = x + (size_t)(tok_list[e * CAP + s] >> 3) * DH + k;
            const float4 v0 = *(const float4*)(xr);
            const float4 v1 = *(const float4*)(xr + 4);
            o[0] = f2bf(v0.x); o[1] = f2bf(v0.y); o[2] = f2bf(v0.z); o[3] = f2bf(v0.w);
            o[4] = f2bf(v1.x); o[5] = f2bf(v1.y); o[6] = f2bf(v1.z); o[7] = f2bf(v1.w);
        }
        *(short8*)(dste + (size_t)s * DH + k) = o;
    }
}

// ---------------- Gateup: 2 waves/block (wave0=gate, wave1=up), 2-deep DMA pipeline ----
// grid (FFD/64=12, NE); block 128. LDS 32KB/block -> 5 blocks (10 waves)/CU.
__global__ __launch_bounds__(128) void moe_gateup(
    const short* __restrict__ xgb,
    const float* __restrict__ wgp, const float* __restrict__ wup,
    short* __restrict__ hc)
{
    // [wave][buf][32k x 64f] fp32 = 2*2*8KB = 32KB; wave0 region doubles as G-exchange
    __shared__ __align__(16) float Bsh[2 * 2 * 2048];

    const int e = blockIdx.y;
    const int tid = threadIdx.x;
    const int lane = tid & 63;
    const int wv = tid >> 6;                 // 0: gate, 1: up
    const int fl = lane & 15;
    const int g16 = lane >> 4;
    const int koff = g16 * 8;
    const int f0 = blockIdx.x * 64;
    const int lrow = lane >> 4;              // 4 rows per glds
    const int lcol = (lane & 15) * 4;        // 16 lanes x 16B = 256B contiguous per row

    const short* xge = xgb + (size_t)e * SMAX * DH;
    const float* wsrc = (wv == 0 ? wgp : wup) + (size_t)e * DH * FFD + f0;

    float* myB = &Bsh[wv * 4096];

    f32x4 acc[4][4] = {};   // [nf][fm], one matrix per wave
    short8 aA[4], aB[4];

    auto ISSUE = [&](int t, int buf) {       // 8 glds (8KB tile)
        const int kk = t * 32;
        float* b = myB + buf * 2048;
        #pragma unroll
        for (int g = 0; g < 8; ++g) {
            const size_t ro = (size_t)(kk + g * 4 + lrow) * FFD + lcol;
            glds16(wsrc + ro, b + g * 256);
        }
    };
    auto LOADA = [&](int t, short8 (&a)[4]) {  // 4 vgpr loads
        const int kk = t * 32 + koff;
        #pragma unroll
        for (int fm = 0; fm < 4; ++fm)
            a[fm] = *(const short8*)(xge + (size_t)(fm * 16 + fl) * DH + kk);
    };
    auto COMP = [&](int buf, const short8 (&a)[4]) {
        const float* bp = myB + buf * 2048 + koff * 64 + fl;
        #pragma unroll
        for (int nf = 0; nf < 4; ++nf) {
            short8 bf;
            #pragma unroll
            for (int j = 0; j < 8; ++j) bf[j] = f2bf(bp[nf * 16 + j * 64]);
            #pragma unroll
            for (int fm = 0; fm < 4; ++fm)
                acc[nf][fm] = __builtin_amdgcn_mfma_f32_16x16x32_bf16(a[fm], bf, acc[nf][fm], 0, 0, 0);
        }
    };

    // DH/32 = 64 K-steps, 2-deep: 12 ops/step (8 glds + 4 A), steady queue 24, wait<=12
    ISSUE(0, 0); LOADA(0, aA);
    for (int t = 0; t < 63; ++t) {
        ISSUE(t + 1, (t + 1) & 1);
        if (t & 1) LOADA(t + 1, aA); else LOADA(t + 1, aB);
        vmwait<12>();
        if (t & 1) COMP(1, aB); else COMP(0, aA);
    }
    vmwait<0>();
    COMP(1, aB);   // t=63 (odd)

    // exchange: wave0 parks g-acc in its own (dead) LDS region; wave1 combines.
    float* G = Bsh;   // 4096 floats = wave0's two buffers
    if (wv == 0) {
        #pragma unroll
        for (int nf = 0; nf < 4; ++nf)
            #pragma unroll
            for (int fm = 0; fm < 4; ++fm)
                #pragma unroll
                for (int r = 0; r < 4; ++r) {
                    const int s = fm * 16 + g16 * 4 + r;
                    G[s * 64 + nf * 16 + fl] = acc[nf][fm][r];
                }
    }
    __syncthreads();
    if (wv == 1) {
        short* hce = hc + (size_t)e * SMAX * FFD + f0;
        #pragma unroll
        for (int nf = 0; nf < 4; ++nf)
            #pragma unroll
            for (int fm = 0; fm < 4; ++fm)
                #pragma unroll
                for (int r = 0; r < 4; ++r) {
                    const int s = fm * 16 + g16 * 4 + r;
                    const float g = G[s * 64 + nf * 16 + fl];
                    const float u = acc[nf][fm][r];
                    const float hv = (g / (1.f + __expf(-g))) * u;
                    hce[(size_t)s * FFD + nf * 16 + fl] = f2bf(hv);
                }
    }
}

// ---------------- Down: 1-wave block, 2-deep DMA pipeline, 16KB LDS ----------------
// grid (DH/64=32, NE); block 64.
__global__ __launch_bounds__(64) void moe_down(
    const short* __restrict__ hc, const float* __restrict__ wdp,
    const int* __restrict__ cnt, const int* __restrict__ tok_list,
    const float* __restrict__ w_list, float* __restrict__ out)
{
    __shared__ __align__(16) float Bsh[2 * 2048];

    const int e = blockIdx.y;
    int n = cnt[e]; if (n > SMAX) n = SMAX;
    if (n == 0) return;

    const int lane = threadIdx.x;
    const int fl = lane & 15;
    const int g16 = lane >> 4;
    const int koff = g16 * 8;
    const int d0 = blockIdx.x * 64;
    const int lrow = lane >> 4;
    const int lcol = (lane & 15) * 4;

    const short* hce = hc + (size_t)e * SMAX * FFD;
    const float* wds = wdp + (size_t)e * FFD * DH + d0;

    f32x4 acc[4][4] = {};   // [nf][fm]
    short8 aA[4], aB[4];

    auto ISSUE = [&](int t, int buf) {       // 8 glds
        const int kk = t * 32;
        float* bd = &Bsh[buf * 2048];
        #pragma unroll
        for (int g = 0; g < 8; ++g) {
            const size_t ro = (size_t)(kk + g * 4 + lrow) * DH + lcol;
            glds16(wds + ro, bd + g * 256);
        }
    };
    auto LOADA = [&](int t, short8 (&a)[4]) {
        const int kk = t * 32 + koff;
        #pragma unroll
        for (int fm = 0; fm < 4; ++fm)
            a[fm] = *(const short8*)(hce + (size_t)(fm * 16 + fl) * FFD + kk);
    };
    auto COMP = [&](int buf, const short8 (&a)[4]) {
        const float* bp = &Bsh[buf * 2048 + koff * 64 + fl];
        #pragma unroll
        for (int nf = 0; nf < 4; ++nf) {
            short8 bf;
            #pragma unroll
            for (int j = 0; j < 8; ++j) bf[j] = f2bf(bp[nf * 16 + j * 64]);
            #pragma unroll
            for (int fm = 0; fm < 4; ++fm)
                acc[nf][fm] = __builtin_amdgcn_mfma_f32_16x16x32_bf16(a[fm], bf, acc[nf][fm], 0, 0, 0);
        }
    };

    // FFD/32 = 24 K-steps, 2-deep: 12 ops/step, wait<=12
    ISSUE(0, 0); LOADA(0, aA);
    for (int t = 0; t < 23; ++t) {
        ISSUE(t + 1, (t + 1) & 1);
        if (t & 1) LOADA(t + 1, aA); else LOADA(t + 1, aB);
        vmwait<12>();
        if (t & 1) COMP(1, aB); else COMP(0, aA);
    }
    vmwait<0>();
    COMP(1, aB);   // t=23 (odd)

    #pragma unroll
    for (int nf = 0; nf < 4; ++nf) {
        #pragma unroll
        for (int fm = 0; fm < 4; ++fm) {
            #pragma unroll
            for (int r = 0; r < 4; ++r) {
                const int s = fm * 16 + g16 * 4 + r;
                if (s < n) {
                    const int t = tok_list[e * CAP + s] >> 3;
                    const float wt = w_list[e * CAP + s];
                    atomicAdd(out + (size_t)t * DH + d0 + nf * 16 + fl, acc[nf][fm][r] * wt);
                }
            }
        }
    }
}

extern "C" void kernel_launch(void* const* d_in, const int* in_sizes, int n_in,
                              void* d_out, int out_size, void* d_ws, size_t ws_size,
                              hipStream_t stream) {
    const float* x   = (const float*)d_in[0];
    const float* wg  = (const float*)d_in[1];
    const float* wgp = (const float*)d_in[2];
    const float* wup = (const float*)d_in[3];
    const float* wdp = (const float*)d_in[4];
    float* out = (float*)d_out;

    char* ws = (char*)d_ws;
    int*   cnt      = (int*)ws;                              // 512 B
    int*   tok_list = (int*)(ws + 1024);                     // 256 KB
    float* w_list   = (float*)(ws + 1024 + NE * CAP * 4);    // 256 KB
    short* xgb      = (short*)(ws + (1 << 20));              // 32 MB
    short* hc       = (short*)(ws + (1 << 20) + (size_t)NE * SMAX * DH * 2);  // 12 MB

    moe_init<<<1, 128, 0, stream>>>(cnt);
    moe_router<<<TT, 128, 0, stream>>>(x, wg, cnt, tok_list, w_list, out);
    moe_gather<<<NE, 256, 0, stream>>>(x, cnt, tok_list, xgb);
    moe_gateup<<<dim3(FFD / 64, NE), 128, 0, stream>>>(xgb, wgp, wup, hc);
    moe_down<<<dim3(DH / 64, NE), 64, 0, stream>>>(hc, wdp, cnt, tok_list, w_list, out);
}

// Round 12
// 806.233 us; speedup vs baseline: 1.0621x; 1.0621x over previous
//
#include <hip/hip_runtime.h>
#include <hip/hip_bf16.h>

#define TT 512
#define DH 2048
#define FFD 768
#define NE 128
#define TOPK 8
#define CAP 512
#define SMAX 64

typedef __attribute__((ext_vector_type(4))) float f32x4;
typedef __attribute__((ext_vector_type(8))) short short8;

typedef __attribute__((address_space(3))) unsigned int lds_u32_t;
typedef __attribute__((address_space(1))) unsigned int glob_u32_t;

__device__ __forceinline__ short f2bf(float f) {
    __hip_bfloat16 h = __float2bfloat16(f);
    return *reinterpret_cast<short*>(&h);
}

// async DMA: 16B/lane, global -> LDS (per-lane global src, wave-uniform LDS dest + lane*16)
__device__ __forceinline__ void glds16(const float* g, float* l) {
    __builtin_amdgcn_global_load_lds((glob_u32_t*)g, (lds_u32_t*)l, 16, 0, 0);
}

template<int N>
__device__ __forceinline__ void vmwait() {
    asm volatile("s_waitcnt vmcnt(%0)" :: "i"(N) : "memory");
}

#define SBAR() __builtin_amdgcn_s_barrier()

// ---------------- Init: zero cnt only ----------------
__global__ __launch_bounds__(128) void moe_init(int* __restrict__ cnt)
{
    cnt[threadIdx.x] = 0;
}

// ---------------- Router (also zeroes its token's output row) ----------------
__global__ __launch_bounds__(128) void moe_router(
    const float* __restrict__ x, const float* __restrict__ wg,
    int* __restrict__ cnt, int* __restrict__ tok_list, float* __restrict__ w_list,
    float* __restrict__ out)
{
    const int t = blockIdx.x;
    const int e = threadIdx.x;
    __shared__ float xs[DH];
    __shared__ float red[NE];
    __shared__ int   redi[NE];
    __shared__ float selw[TOPK];
    __shared__ int   seli[TOPK];

    float4* outrow = (float4*)(out + (size_t)t * DH);
    const float4 z4 = make_float4(0.f, 0.f, 0.f, 0.f);
    #pragma unroll
    for (int i = 0; i < 4; ++i) outrow[e + i * 128] = z4;

    for (int i = e; i < DH; i += 128) xs[i] = x[(size_t)t * DH + i];
    __syncthreads();

    float acc = 0.f;
    #pragma unroll 4
    for (int d = 0; d < DH; ++d)
        acc = fmaf(xs[d], wg[(size_t)d * NE + e], acc);

    red[e] = acc; __syncthreads();
    for (int s = 64; s > 0; s >>= 1) {
        if (e < s) red[e] = fmaxf(red[e], red[e + s]);
        __syncthreads();
    }
    const float mx = red[0];
    __syncthreads();

    float myp = __expf(acc - mx);

    for (int k = 0; k < TOPK; ++k) {
        red[e] = myp; redi[e] = e;
        __syncthreads();
        for (int s = 64; s > 0; s >>= 1) {
            if (e < s) {
                const float v2 = red[e + s]; const int i2 = redi[e + s];
                if (v2 > red[e] || (v2 == red[e] && i2 < redi[e])) { red[e] = v2; redi[e] = i2; }
            }
            __syncthreads();
        }
        if (e == 0) { selw[k] = red[0]; seli[k] = redi[0]; }
        __syncthreads();
        if (e == seli[k]) myp = -1.f;
        __syncthreads();
    }

    if (e == 0) {
        float s8 = 0.f;
        #pragma unroll
        for (int k = 0; k < TOPK; ++k) s8 += selw[k];
        const float inv = 1.f / s8;
        #pragma unroll
        for (int k = 0; k < TOPK; ++k) {
            const int ex = seli[k];
            const float wv = selw[k] * inv;
            const int pos = atomicAdd(&cnt[ex], 1);
            if (pos < CAP) {
                tok_list[ex * CAP + pos] = t * TOPK + k;
                w_list[ex * CAP + pos] = wv;
            }
        }
    }
}

// ---------------- Gather: xgb[e][slot][k] bf16, zero-padded to SMAX rows ----------------
__global__ __launch_bounds__(256) void moe_gather(
    const float* __restrict__ x, const int* __restrict__ cnt,
    const int* __restrict__ tok_list, short* __restrict__ xgb)
{
    const int e = blockIdx.x;
    int n = cnt[e]; if (n > SMAX) n = SMAX;
    const int k = threadIdx.x * 8;
    short* dste = xgb + (size_t)e * SMAX * DH;
    for (int s = 0; s < SMAX; ++s) {
        short8 o = {0, 0, 0, 0, 0, 0, 0, 0};
        if (s < n) {
            const float* xr = x + (size_t)(tok_list[e * CAP + s] >> 3) * DH + k;
            const float4 v0 = *(const float4*)(xr);
            const float4 v1 = *(const float4*)(xr + 4);
            o[0] = f2bf(v0.x); o[1] = f2bf(v0.y); o[2] = f2bf(v0.z); o[3] = f2bf(v0.w);
            o[4] = f2bf(v1.x); o[5] = f2bf(v1.y); o[6] = f2bf(v1.z); o[7] = f2bf(v1.w);
        }
        *(short8*)(dste + (size_t)s * DH + k) = o;
    }
}

// ---------------- Gateup: 4-wave cooperative tile, BN=192 (768B runs) ----------------
// grid (FFD/192=4, NE); block 256. LDS [2 mats][2 bufs][32x192] f32 = 96KB.
__global__ __launch_bounds__(256) void moe_gateup(
    const short* __restrict__ xgb,
    const float* __restrict__ wgp, const float* __restrict__ wup,
    short* __restrict__ hc)
{
    __shared__ __align__(16) float Bsh[2 * 2 * 6144];

    const int e = blockIdx.y;
    const int tid = threadIdx.x;
    const int lane = tid & 63;
    const int wv = tid >> 6;
    const int fl = lane & 15;
    const int g16 = lane >> 4;
    const int koff = g16 * 8;
    const int c0 = blockIdx.x * 192;

    const short* xge = xgb + (size_t)e * SMAX * DH;
    const float* wgs = wgp + (size_t)e * DH * FFD + c0;
    const float* wus = wup + (size_t)e * DH * FFD + c0;

    // per-lane (row,col) offsets for this wave's 6 glds slots of the flat [32][192] tile
    int goff[6];
    #pragma unroll
    for (int i = 0; i < 6; ++i) {
        const int o = (wv * 6 + i) * 256 + lane * 4;   // flat float offset in tile
        const int r = o / 192;
        goff[i] = r * FFD + (o - r * 192);             // global float offset (row-major weights)
    }

    f32x4 accg[3][4] = {};   // [nf][fm]
    f32x4 accu[3][4] = {};
    short8 aA[4], aB[4];

    auto ISSUE = [&](int t, int buf) {                 // 12 glds/wave (6 per matrix)
        const int kk = t * 32;
        const float* wg_k = wgs + (size_t)kk * FFD;
        const float* wu_k = wus + (size_t)kk * FFD;
        float* lg = &Bsh[buf * 6144];
        float* lu = &Bsh[2 * 6144 + buf * 6144];
        #pragma unroll
        for (int i = 0; i < 6; ++i) {
            const int q = wv * 6 + i;
            glds16(wg_k + goff[i], lg + q * 256);
            glds16(wu_k + goff[i], lu + q * 256);
        }
    };
    auto LOADA = [&](int t, short8 (&a)[4]) {          // 4 loads (xgb, L2-hot)
        const int kk = t * 32 + koff;
        #pragma unroll
        for (int fm = 0; fm < 4; ++fm)
            a[fm] = *(const short8*)(xge + (size_t)(fm * 16 + fl) * DH + kk);
    };
    auto COMP = [&](int buf, const short8 (&a)[4]) {
        const float* lg = &Bsh[buf * 6144 + koff * 192 + wv * 48 + fl];
        const float* lu = &Bsh[2 * 6144 + buf * 6144 + koff * 192 + wv * 48 + fl];
        #pragma unroll
        for (int nf = 0; nf < 3; ++nf) {
            short8 bg, bu;
            #pragma unroll
            for (int j = 0; j < 8; ++j) {
                bg[j] = f2bf(lg[nf * 16 + j * 192]);
                bu[j] = f2bf(lu[nf * 16 + j * 192]);
            }
            #pragma unroll
            for (int fm = 0; fm < 4; ++fm) {
                accg[nf][fm] = __builtin_amdgcn_mfma_f32_16x16x32_bf16(a[fm], bg, accg[nf][fm], 0, 0, 0);
                accu[nf][fm] = __builtin_amdgcn_mfma_f32_16x16x32_bf16(a[fm], bu, accu[nf][fm], 0, 0, 0);
            }
        }
    };

    // DH/32 = 64 K-steps. Per wave/step: 12 glds + 4 A; vmcnt(16) leaves next step in flight.
    ISSUE(0, 0); LOADA(0, aA);
    for (int t = 0; t < 63; ++t) {
        ISSUE(t + 1, (t + 1) & 1);
        if (t & 1) LOADA(t + 1, aA); else LOADA(t + 1, aB);
        vmwait<16>();
        SBAR();                      // all waves' step-t tile landed (prefetch t+1 in flight)
        if (t & 1) COMP(1, aB); else COMP(0, aA);
        SBAR();                      // all waves done reading buf t&1 before it's rewritten
    }
    vmwait<0>();
    SBAR();
    COMP(1, aB);                     // t=63

    short* hce = hc + (size_t)e * SMAX * FFD + c0 + wv * 48 + fl;
    #pragma unroll
    for (int nf = 0; nf < 3; ++nf) {
        #pragma unroll
        for (int fm = 0; fm < 4; ++fm) {
            #pragma unroll
            for (int r = 0; r < 4; ++r) {
                const int s = fm * 16 + g16 * 4 + r;
                const float g = accg[nf][fm][r];
                const float u = accu[nf][fm][r];
                const float hv = (g / (1.f + __expf(-g))) * u;
                hce[(size_t)s * FFD + nf * 16] = f2bf(hv);
            }
        }
    }
}

// ---------------- Down: 4-wave cooperative tile, BN=256 (1KB runs) ----------------
// grid (DH/256=8, NE); block 256. LDS [2 bufs][32x256] f32 = 64KB.
__global__ __launch_bounds__(256) void moe_down(
    const short* __restrict__ hc, const float* __restrict__ wdp,
    const int* __restrict__ cnt, const int* __restrict__ tok_list,
    const float* __restrict__ w_list, float* __restrict__ out)
{
    __shared__ __align__(16) float Bsh[2 * 8192];

    const int e = blockIdx.y;
    int n = cnt[e]; if (n > SMAX) n = SMAX;
    if (n == 0) return;

    const int tid = threadIdx.x;
    const int lane = tid & 63;
    const int wv = tid >> 6;
    const int fl = lane & 15;
    const int g16 = lane >> 4;
    const int koff = g16 * 8;
    const int d0 = blockIdx.x * 256;

    const short* hce = hc + (size_t)e * SMAX * FFD;
    const float* wds = wdp + (size_t)e * FFD * DH + d0;

    f32x4 acc[4][4] = {};   // [nf][fm]
    short8 aA[4], aB[4];

    auto ISSUE = [&](int t, int buf) {                 // 8 glds/wave, 1 row x 1024B each
        const int kk = t * 32;
        float* ld = &Bsh[buf * 8192];
        #pragma unroll
        for (int i = 0; i < 8; ++i) {
            const int row = wv * 8 + i;
            glds16(wds + (size_t)(kk + row) * DH + lane * 4, ld + row * 256);
        }
    };
    auto LOADA = [&](int t, short8 (&a)[4]) {
        const int kk = t * 32 + koff;
        #pragma unroll
        for (int fm = 0; fm < 4; ++fm)
            a[fm] = *(const short8*)(hce + (size_t)(fm * 16 + fl) * FFD + kk);
    };
    auto COMP = [&](int buf, const short8 (&a)[4]) {
        const float* bp = &Bsh[buf * 8192 + koff * 256 + wv * 64 + fl];
        #pragma unroll
        for (int nf = 0; nf < 4; ++nf) {
            short8 bf;
            #pragma unroll
            for (int j = 0; j < 8; ++j) bf[j] = f2bf(bp[nf * 16 + j * 256]);
            #pragma unroll
            for (int fm = 0; fm < 4; ++fm)
                acc[nf][fm] = __builtin_amdgcn_mfma_f32_16x16x32_bf16(a[fm], bf, acc[nf][fm], 0, 0, 0);
        }
    };

    // FFD/32 = 24 K-steps. Per wave/step: 8 glds + 4 A; vmcnt(12).
    ISSUE(0, 0); LOADA(0, aA);
    for (int t = 0; t < 23; ++t) {
        ISSUE(t + 1, (t + 1) & 1);
        if (t & 1) LOADA(t + 1, aA); else LOADA(t + 1, aB);
        vmwait<12>();
        SBAR();
        if (t & 1) COMP(1, aB); else COMP(0, aA);
        SBAR();
    }
    vmwait<0>();
    SBAR();
    COMP(1, aB);                     // t=23

    #pragma unroll
    for (int nf = 0; nf < 4; ++nf) {
        #pragma unroll
        for (int fm = 0; fm < 4; ++fm) {
            #pragma unroll
            for (int r = 0; r < 4; ++r) {
                const int s = fm * 16 + g16 * 4 + r;
                if (s < n) {
                    const int t = tok_list[e * CAP + s] >> 3;
                    const float wt = w_list[e * CAP + s];
                    atomicAdd(out + (size_t)t * DH + d0 + wv * 64 + nf * 16 + fl, acc[nf][fm][r] * wt);
                }
            }
        }
    }
}

extern "C" void kernel_launch(void* const* d_in, const int* in_sizes, int n_in,
                              void* d_out, int out_size, void* d_ws, size_t ws_size,
                              hipStream_t stream) {
    const float* x   = (const float*)d_in[0];
    const float* wg  = (const float*)d_in[1];
    const float* wgp = (const float*)d_in[2];
    const float* wup = (const float*)d_in[3];
    const float* wdp = (const float*)d_in[4];
    float* out = (float*)d_out;

    char* ws = (char*)d_ws;
    int*   cnt      = (int*)ws;                              // 512 B
    int*   tok_list = (int*)(ws + 1024);                     // 256 KB
    float* w_list   = (float*)(ws + 1024 + NE * CAP * 4);    // 256 KB
    short* xgb      = (short*)(ws + (1 << 20));              // 32 MB
    short* hc       = (short*)(ws + (1 << 20) + (size_t)NE * SMAX * DH * 2);  // 12 MB

    moe_init<<<1, 128, 0, stream>>>(cnt);
    moe_router<<<TT, 128, 0, stream>>>(x, wg, cnt, tok_list, w_list, out);
    moe_gather<<<NE, 256, 0, stream>>>(x, cnt, tok_list, xgb);
    moe_gateup<<<dim3(FFD / 192, NE), 256, 0, stream>>>(xgb, wgp, wup, hc);
    moe_down<<<dim3(DH / 256, NE), 256, 0, stream>>>(hc, wdp, cnt, tok_list, w_list, out);
}

// Round 13
// 684.826 us; speedup vs baseline: 1.2504x; 1.1773x over previous
//
#include <hip/hip_runtime.h>
#include <hip/hip_bf16.h>

#define TT 512
#define DH 2048
#define FFD 768
#define NE 128
#define TOPK 8
#define CAP 512
#define SMAX 64

typedef __attribute__((ext_vector_type(4))) float f32x4;
typedef __attribute__((ext_vector_type(8))) short short8;

typedef __attribute__((address_space(3))) unsigned int lds_u32_t;
typedef __attribute__((address_space(1))) unsigned int glob_u32_t;

__device__ __forceinline__ short f2bf(float f) {
    __hip_bfloat16 h = __float2bfloat16(f);
    return *reinterpret_cast<short*>(&h);
}

// async DMA: 16B/lane, global -> LDS. Cached variant (A/hc) and NT variant (weights:
// read-once 2.42GB stream -> no L2 allocate, keep the miss path free of evict work).
__device__ __forceinline__ void glds16(const float* g, float* l) {
    __builtin_amdgcn_global_load_lds((glob_u32_t*)g, (lds_u32_t*)l, 16, 0, 0);
}
__device__ __forceinline__ void glds16nt(const float* g, float* l) {
    __builtin_amdgcn_global_load_lds((glob_u32_t*)g, (lds_u32_t*)l, 16, 0, 2 /*NT*/);
}

template<int N>
__device__ __forceinline__ void vmwait() {
    asm volatile("s_waitcnt vmcnt(%0)" :: "i"(N) : "memory");
}

// ---------------- Init: zero cnt only ----------------
__global__ __launch_bounds__(128) void moe_init(int* __restrict__ cnt)
{
    cnt[threadIdx.x] = 0;
}

// ---------------- Router (also zeroes its token's output row) ----------------
__global__ __launch_bounds__(128) void moe_router(
    const float* __restrict__ x, const float* __restrict__ wg,
    int* __restrict__ cnt, int* __restrict__ tok_list, float* __restrict__ w_list,
    float* __restrict__ out)
{
    const int t = blockIdx.x;
    const int e = threadIdx.x;
    __shared__ float xs[DH];
    __shared__ float red[NE];
    __shared__ int   redi[NE];
    __shared__ float selw[TOPK];
    __shared__ int   seli[TOPK];

    float4* outrow = (float4*)(out + (size_t)t * DH);
    const float4 z4 = make_float4(0.f, 0.f, 0.f, 0.f);
    #pragma unroll
    for (int i = 0; i < 4; ++i) outrow[e + i * 128] = z4;

    for (int i = e; i < DH; i += 128) xs[i] = x[(size_t)t * DH + i];
    __syncthreads();

    float acc = 0.f;
    #pragma unroll 4
    for (int d = 0; d < DH; ++d)
        acc = fmaf(xs[d], wg[(size_t)d * NE + e], acc);

    red[e] = acc; __syncthreads();
    for (int s = 64; s > 0; s >>= 1) {
        if (e < s) red[e] = fmaxf(red[e], red[e + s]);
        __syncthreads();
    }
    const float mx = red[0];
    __syncthreads();

    float myp = __expf(acc - mx);

    for (int k = 0; k < TOPK; ++k) {
        red[e] = myp; redi[e] = e;
        __syncthreads();
        for (int s = 64; s > 0; s >>= 1) {
            if (e < s) {
                const float v2 = red[e + s]; const int i2 = redi[e + s];
                if (v2 > red[e] || (v2 == red[e] && i2 < redi[e])) { red[e] = v2; redi[e] = i2; }
            }
            __syncthreads();
        }
        if (e == 0) { selw[k] = red[0]; seli[k] = redi[0]; }
        __syncthreads();
        if (e == seli[k]) myp = -1.f;
        __syncthreads();
    }

    if (e == 0) {
        float s8 = 0.f;
        #pragma unroll
        for (int k = 0; k < TOPK; ++k) s8 += selw[k];
        const float inv = 1.f / s8;
        #pragma unroll
        for (int k = 0; k < TOPK; ++k) {
            const int ex = seli[k];
            const float wv = selw[k] * inv;
            const int pos = atomicAdd(&cnt[ex], 1);
            if (pos < CAP) {
                tok_list[ex * CAP + pos] = t * TOPK + k;
                w_list[ex * CAP + pos] = wv;
            }
        }
    }
}

// ---------------- Gather: xgb[e][slot][k] bf16, zero-padded; 8 slots per block ----------------
// grid (NE, 8); block 256
__global__ __launch_bounds__(256) void moe_gather(
    const float* __restrict__ x, const int* __restrict__ cnt,
    const int* __restrict__ tok_list, short* __restrict__ xgb)
{
    const int e = blockIdx.x;
    int n = cnt[e]; if (n > SMAX) n = SMAX;
    const int s0 = blockIdx.y * 8;
    const int k = threadIdx.x * 8;
    short* dste = xgb + (size_t)e * SMAX * DH;
    #pragma unroll
    for (int i = 0; i < 8; ++i) {
        const int s = s0 + i;
        short8 o = {0, 0, 0, 0, 0, 0, 0, 0};
        if (s < n) {
            const float* xr = x + (size_t)(tok_list[e * CAP + s] >> 3) * DH + k;
            const float4 v0 = *(const float4*)(xr);
            const float4 v1 = *(const float4*)(xr + 4);
            o[0] = f2bf(v0.x); o[1] = f2bf(v0.y); o[2] = f2bf(v0.z); o[3] = f2bf(v0.w);
            o[4] = f2bf(v1.x); o[5] = f2bf(v1.y); o[6] = f2bf(v1.z); o[7] = f2bf(v1.w);
        }
        *(short8*)(dste + (size_t)s * DH + k) = o;
    }
}

// ---------------- Gateup: 3-deep DMA pipeline, 1-wave block, 64 slots x 64 f ----------------
// grid (FFD/64=12, NE); block 64. LDS: 3 bufs x (2 mat x 8KB) = 48KB.
__global__ __launch_bounds__(64) void moe_gateup(
    const short* __restrict__ xgb,
    const float* __restrict__ wgp, const float* __restrict__ wup,
    short* __restrict__ hc)
{
    __shared__ __align__(16) float Bsh[6 * 2048];   // bg: bufs 0..2 at 0/2048/4096; bu at +6144

    const int e = blockIdx.y;
    const int lane = threadIdx.x;
    const int fl = lane & 15;
    const int g16 = lane >> 4;
    const int koff = g16 * 8;
    const int f0 = blockIdx.x * 64;
    const int lrow = lane >> 4;              // 4 rows per glds
    const int lcol = (lane & 15) * 4;        // 16 lanes x 16B = 256B contiguous per row

    const short* xge = xgb + (size_t)e * SMAX * DH;
    const float* wgs = wgp + (size_t)e * DH * FFD + f0;
    const float* wus = wup + (size_t)e * DH * FFD + f0;

    f32x4 accg[4][4] = {};   // [nf][fm]
    f32x4 accu[4][4] = {};
    short8 A0[4], A1[4], A2[4];

    auto ISSUE = [&](int t, int buf) {       // 16 glds (NT: read-once weight stream)
        const int kk = t * 32;
        float* bg = &Bsh[buf * 2048];
        float* bu = &Bsh[6144 + buf * 2048];
        #pragma unroll
        for (int g = 0; g < 8; ++g) {
            const size_t ro = (size_t)(kk + g * 4 + lrow) * FFD + lcol;
            glds16nt(wgs + ro, bg + g * 256);
            glds16nt(wus + ro, bu + g * 256);
        }
    };
    auto LOADA = [&](int t, short8 (&a)[4]) {  // 4 vgpr loads (xgb: L2-hot, cached)
        const int kk = t * 32 + koff;
        #pragma unroll
        for (int fm = 0; fm < 4; ++fm)
            a[fm] = *(const short8*)(xge + (size_t)(fm * 16 + fl) * DH + kk);
    };
    auto COMP = [&](int buf, const short8 (&a)[4]) {
        const float* bg = &Bsh[buf * 2048 + koff * 64 + fl];
        const float* bu = &Bsh[6144 + buf * 2048 + koff * 64 + fl];
        #pragma unroll
        for (int nf = 0; nf < 4; ++nf) {
            short8 bfg, bfu;
            #pragma unroll
            for (int j = 0; j < 8; ++j) {
                bfg[j] = f2bf(bg[nf * 16 + j * 64]);
                bfu[j] = f2bf(bu[nf * 16 + j * 64]);
            }
            #pragma unroll
            for (int fm = 0; fm < 4; ++fm) {
                accg[nf][fm] = __builtin_amdgcn_mfma_f32_16x16x32_bf16(a[fm], bfg, accg[nf][fm], 0, 0, 0);
                accu[nf][fm] = __builtin_amdgcn_mfma_f32_16x16x32_bf16(a[fm], bfu, accu[nf][fm], 0, 0, 0);
            }
        }
    };

    // DH/32 = 64 K-steps; step t -> buf/Aset t%3. Steady state: 2 steps (40 ops) in flight.
    LOADA(0, A0); ISSUE(0, 0);
    LOADA(1, A1); ISSUE(1, 1);
    for (int i = 0; i < 20; ++i) {           // computes t = 0..59
        const int t = 3 * i;
        LOADA(t + 2, A2); ISSUE(t + 2, 2); vmwait<40>(); COMP(0, A0);
        LOADA(t + 3, A0); ISSUE(t + 3, 0); vmwait<40>(); COMP(1, A1);
        LOADA(t + 4, A1); ISSUE(t + 4, 1); vmwait<40>(); COMP(2, A2);
    }
    LOADA(62, A2); ISSUE(62, 2); vmwait<40>(); COMP(0, A0);   // t=60
    LOADA(63, A0); ISSUE(63, 0); vmwait<40>(); COMP(1, A1);   // t=61
    vmwait<20>(); COMP(2, A2);                                 // t=62
    vmwait<0>();  COMP(0, A0);                                 // t=63

    short* hce = hc + (size_t)e * SMAX * FFD + f0;
    #pragma unroll
    for (int nf = 0; nf < 4; ++nf) {
        #pragma unroll
        for (int fm = 0; fm < 4; ++fm) {
            #pragma unroll
            for (int r = 0; r < 4; ++r) {
                const int s = fm * 16 + g16 * 4 + r;
                const float g = accg[nf][fm][r];
                const float u = accu[nf][fm][r];
                const float hv = (g / (1.f + __expf(-g))) * u;
                hce[(size_t)s * FFD + nf * 16 + fl] = f2bf(hv);
            }
        }
    }
}

// ---------------- Down: 3-deep DMA pipeline, 1-wave block, 64 slots x 64 d ----------------
// grid (DH/64=32, NE); block 64. LDS: 3 bufs x 8KB = 24KB.
__global__ __launch_bounds__(64) void moe_down(
    const short* __restrict__ hc, const float* __restrict__ wdp,
    const int* __restrict__ cnt, const int* __restrict__ tok_list,
    const float* __restrict__ w_list, float* __restrict__ out)
{
    __shared__ __align__(16) float Bsh[3 * 2048];

    const int e = blockIdx.y;
    int n = cnt[e]; if (n > SMAX) n = SMAX;
    if (n == 0) return;

    const int lane = threadIdx.x;
    const int fl = lane & 15;
    const int g16 = lane >> 4;
    const int koff = g16 * 8;
    const int d0 = blockIdx.x * 64;
    const int lrow = lane >> 4;
    const int lcol = (lane & 15) * 4;

    const short* hce = hc + (size_t)e * SMAX * FFD;
    const float* wds = wdp + (size_t)e * FFD * DH + d0;

    f32x4 acc[4][4] = {};   // [nf][fm]
    short8 A0[4], A1[4], A2[4];

    auto ISSUE = [&](int t, int buf) {       // 8 glds (NT)
        const int kk = t * 32;
        float* bd = &Bsh[buf * 2048];
        #pragma unroll
        for (int g = 0; g < 8; ++g) {
            const size_t ro = (size_t)(kk + g * 4 + lrow) * DH + lcol;
            glds16nt(wds + ro, bd + g * 256);
        }
    };
    auto LOADA = [&](int t, short8 (&a)[4]) {
        const int kk = t * 32 + koff;
        #pragma unroll
        for (int fm = 0; fm < 4; ++fm)
            a[fm] = *(const short8*)(hce + (size_t)(fm * 16 + fl) * FFD + kk);
    };
    auto COMP = [&](int buf, const short8 (&a)[4]) {
        const float* bp = &Bsh[buf * 2048 + koff * 64 + fl];
        #pragma unroll
        for (int nf = 0; nf < 4; ++nf) {
            short8 bf;
            #pragma unroll
            for (int j = 0; j < 8; ++j) bf[j] = f2bf(bp[nf * 16 + j * 64]);
            #pragma unroll
            for (int fm = 0; fm < 4; ++fm)
                acc[nf][fm] = __builtin_amdgcn_mfma_f32_16x16x32_bf16(a[fm], bf, acc[nf][fm], 0, 0, 0);
        }
    };

    // FFD/32 = 24 K-steps; per step 12 ops (8 glds + 4 A); steady 24 in flight.
    LOADA(0, A0); ISSUE(0, 0);
    LOADA(1, A1); ISSUE(1, 1);
    for (int i = 0; i < 6; ++i) {            // computes t = 0..17
        const int t = 3 * i;
        LOADA(t + 2, A2); ISSUE(t + 2, 2); vmwait<24>(); COMP(0, A0);
        LOADA(t + 3, A0); ISSUE(t + 3, 0); vmwait<24>(); COMP(1, A1);
        LOADA(t + 4, A1); ISSUE(t + 4, 1); vmwait<24>(); COMP(2, A2);
    }
    LOADA(20, A2); ISSUE(20, 2); vmwait<24>(); COMP(0, A0);   // t=18
    LOADA(21, A0); ISSUE(21, 0); vmwait<24>(); COMP(1, A1);   // t=19
    LOADA(22, A1); ISSUE(22, 1); vmwait<24>(); COMP(2, A2);   // t=20
    LOADA(23, A2); ISSUE(23, 2); vmwait<24>(); COMP(0, A0);   // t=21
    vmwait<12>(); COMP(1, A1);                                 // t=22
    vmwait<0>();  COMP(2, A2);                                 // t=23

    #pragma unroll
    for (int nf = 0; nf < 4; ++nf) {
        #pragma unroll
        for (int fm = 0; fm < 4; ++fm) {
            #pragma unroll
            for (int r = 0; r < 4; ++r) {
                const int s = fm * 16 + g16 * 4 + r;
                if (s < n) {
                    const int t = tok_list[e * CAP + s] >> 3;
                    const float wt = w_list[e * CAP + s];
                    atomicAdd(out + (size_t)t * DH + d0 + nf * 16 + fl, acc[nf][fm][r] * wt);
                }
            }
        }
    }
}

extern "C" void kernel_launch(void* const* d_in, const int* in_sizes, int n_in,
                              void* d_out, int out_size, void* d_ws, size_t ws_size,
                              hipStream_t stream) {
    const float* x   = (const float*)d_in[0];
    const float* wg  = (const float*)d_in[1];
    const float* wgp = (const float*)d_in[2];
    const float* wup = (const float*)d_in[3];
    const float* wdp = (const float*)d_in[4];
    float* out = (float*)d_out;

    char* ws = (char*)d_ws;
    int*   cnt      = (int*)ws;                              // 512 B
    int*   tok_list = (int*)(ws + 1024);                     // 256 KB
    float* w_list   = (float*)(ws + 1024 + NE * CAP * 4);    // 256 KB
    short* xgb      = (short*)(ws + (1 << 20));              // 32 MB
    short* hc       = (short*)(ws + (1 << 20) + (size_t)NE * SMAX * DH * 2);  // 12 MB

    moe_init<<<1, 128, 0, stream>>>(cnt);
    moe_router<<<TT, 128, 0, stream>>>(x, wg, cnt, tok_list, w_list, out);
    moe_gather<<<dim3(NE, 8), 256, 0, stream>>>(x, cnt, tok_list, xgb);
    moe_gateup<<<dim3(FFD / 64, NE), 64, 0, stream>>>(xgb, wgp, wup, hc);
    moe_down<<<dim3(DH / 64, NE), 64, 0, stream>>>(hc, wdp, cnt, tok_list, w_list, out);
}

// Round 14
// 673.390 us; speedup vs baseline: 1.2716x; 1.0170x over previous
//
#include <hip/hip_runtime.h>
#include <hip/hip_bf16.h>

#define TT 512
#define DH 2048
#define FFD 768
#define NE 128
#define TOPK 8
#define CAP 512
#define SMAX 64

typedef __attribute__((ext_vector_type(4))) float f32x4;
typedef __attribute__((ext_vector_type(8))) short short8;

typedef __attribute__((address_space(3))) unsigned int lds_u32_t;
typedef __attribute__((address_space(1))) unsigned int glob_u32_t;

__device__ __forceinline__ short f2bf(float f) {
    __hip_bfloat16 h = __float2bfloat16(f);
    return *reinterpret_cast<short*>(&h);
}

// async DMA: 16B/lane, global -> LDS. Cached (A/hc) and NT (read-once weights).
__device__ __forceinline__ void glds16(const float* g, float* l) {
    __builtin_amdgcn_global_load_lds((glob_u32_t*)g, (lds_u32_t*)l, 16, 0, 0);
}
__device__ __forceinline__ void glds16nt(const float* g, float* l) {
    __builtin_amdgcn_global_load_lds((glob_u32_t*)g, (lds_u32_t*)l, 16, 0, 2 /*NT*/);
}

template<int N>
__device__ __forceinline__ void vmwait() {
    asm volatile("s_waitcnt vmcnt(%0)" :: "i"(N) : "memory");
}
#define LGKM0() do { asm volatile("s_waitcnt lgkmcnt(0)" ::: "memory"); __builtin_amdgcn_sched_barrier(0); } while (0)

// ---------------- Init: zero cnt only ----------------
__global__ __launch_bounds__(128) void moe_init(int* __restrict__ cnt)
{
    cnt[threadIdx.x] = 0;
}

// ---------------- Router ----------------
__global__ __launch_bounds__(128) void moe_router(
    const float* __restrict__ x, const float* __restrict__ wg,
    int* __restrict__ cnt, int* __restrict__ tok_list, float* __restrict__ w_list)
{
    const int t = blockIdx.x;
    const int e = threadIdx.x;
    __shared__ float xs[DH];
    __shared__ float red[NE];
    __shared__ int   redi[NE];
    __shared__ float selw[TOPK];
    __shared__ int   seli[TOPK];

    for (int i = e; i < DH; i += 128) xs[i] = x[(size_t)t * DH + i];
    __syncthreads();

    float acc = 0.f;
    #pragma unroll 4
    for (int d = 0; d < DH; ++d)
        acc = fmaf(xs[d], wg[(size_t)d * NE + e], acc);

    red[e] = acc; __syncthreads();
    for (int s = 64; s > 0; s >>= 1) {
        if (e < s) red[e] = fmaxf(red[e], red[e + s]);
        __syncthreads();
    }
    const float mx = red[0];
    __syncthreads();

    float myp = __expf(acc - mx);

    for (int k = 0; k < TOPK; ++k) {
        red[e] = myp; redi[e] = e;
        __syncthreads();
        for (int s = 64; s > 0; s >>= 1) {
            if (e < s) {
                const float v2 = red[e + s]; const int i2 = redi[e + s];
                if (v2 > red[e] || (v2 == red[e] && i2 < redi[e])) { red[e] = v2; redi[e] = i2; }
            }
            __syncthreads();
        }
        if (e == 0) { selw[k] = red[0]; seli[k] = redi[0]; }
        __syncthreads();
        if (e == seli[k]) myp = -1.f;
        __syncthreads();
    }

    if (e == 0) {
        float s8 = 0.f;
        #pragma unroll
        for (int k = 0; k < TOPK; ++k) s8 += selw[k];
        const float inv = 1.f / s8;
        #pragma unroll
        for (int k = 0; k < TOPK; ++k) {
            const int ex = seli[k];
            const float wv = selw[k] * inv;
            const int pos = atomicAdd(&cnt[ex], 1);
            if (pos < CAP) {
                tok_list[ex * CAP + pos] = t * TOPK + k;
                w_list[ex * CAP + pos] = wv;
            }
        }
    }
}

// ---------------- Gather: xgb[e][slot][k] bf16, zero-padded; 8 slots per block ----------------
// grid (NE, 8); block 256
__global__ __launch_bounds__(256) void moe_gather(
    const float* __restrict__ x, const int* __restrict__ cnt,
    const int* __restrict__ tok_list, short* __restrict__ xgb)
{
    const int e = blockIdx.x;
    int n = cnt[e]; if (n > SMAX) n = SMAX;
    const int s0 = blockIdx.y * 8;
    const int k = threadIdx.x * 8;
    short* dste = xgb + (size_t)e * SMAX * DH;
    #pragma unroll
    for (int i = 0; i < 8; ++i) {
        const int s = s0 + i;
        short8 o = {0, 0, 0, 0, 0, 0, 0, 0};
        if (s < n) {
            const float* xr = x + (size_t)(tok_list[e * CAP + s] >> 3) * DH + k;
            const float4 v0 = *(const float4*)(xr);
            const float4 v1 = *(const float4*)(xr + 4);
            o[0] = f2bf(v0.x); o[1] = f2bf(v0.y); o[2] = f2bf(v0.z); o[3] = f2bf(v0.w);
            o[4] = f2bf(v1.x); o[5] = f2bf(v1.y); o[6] = f2bf(v1.z); o[7] = f2bf(v1.w);
        }
        *(short8*)(dste + (size_t)s * DH + k) = o;
    }
}

// ---------------- Gateup: 3-deep NT-DMA pipeline, 1-wave block, 64 slots x 64 f ----------------
// grid (FFD/64=12, NE); block 64. LDS: 48KB.
__global__ __launch_bounds__(64) void moe_gateup(
    const short* __restrict__ xgb,
    const float* __restrict__ wgp, const float* __restrict__ wup,
    short* __restrict__ hc)
{
    __shared__ __align__(16) float Bsh[6 * 2048];

    const int e = blockIdx.y;
    const int lane = threadIdx.x;
    const int fl = lane & 15;
    const int g16 = lane >> 4;
    const int koff = g16 * 8;
    const int f0 = blockIdx.x * 64;
    const int lrow = lane >> 4;
    const int lcol = (lane & 15) * 4;

    const short* xge = xgb + (size_t)e * SMAX * DH;
    const float* wgs = wgp + (size_t)e * DH * FFD + f0;
    const float* wus = wup + (size_t)e * DH * FFD + f0;

    f32x4 accg[4][4] = {};   // [nf][fm]
    f32x4 accu[4][4] = {};
    short8 A0[4], A1[4], A2[4];

    auto ISSUE = [&](int t, int buf) {       // 16 glds (NT weight stream)
        const int kk = t * 32;
        float* bg = &Bsh[buf * 2048];
        float* bu = &Bsh[6144 + buf * 2048];
        #pragma unroll
        for (int g = 0; g < 8; ++g) {
            const size_t ro = (size_t)(kk + g * 4 + lrow) * FFD + lcol;
            glds16nt(wgs + ro, bg + g * 256);
            glds16nt(wus + ro, bu + g * 256);
        }
    };
    auto LOADA = [&](int t, short8 (&a)[4]) {
        const int kk = t * 32 + koff;
        #pragma unroll
        for (int fm = 0; fm < 4; ++fm)
            a[fm] = *(const short8*)(xge + (size_t)(fm * 16 + fl) * DH + kk);
    };
    auto COMP = [&](int buf, const short8 (&a)[4]) {
        const float* bg = &Bsh[buf * 2048 + koff * 64 + fl];
        const float* bu = &Bsh[6144 + buf * 2048 + koff * 64 + fl];
        #pragma unroll
        for (int nf = 0; nf < 4; ++nf) {
            short8 bfg, bfu;
            #pragma unroll
            for (int j = 0; j < 8; ++j) {
                bfg[j] = f2bf(bg[nf * 16 + j * 64]);
                bfu[j] = f2bf(bu[nf * 16 + j * 64]);
            }
            #pragma unroll
            for (int fm = 0; fm < 4; ++fm) {
                accg[nf][fm] = __builtin_amdgcn_mfma_f32_16x16x32_bf16(a[fm], bfg, accg[nf][fm], 0, 0, 0);
                accu[nf][fm] = __builtin_amdgcn_mfma_f32_16x16x32_bf16(a[fm], bfu, accu[nf][fm], 0, 0, 0);
            }
        }
    };

    LOADA(0, A0); ISSUE(0, 0);
    LOADA(1, A1); ISSUE(1, 1);
    for (int i = 0; i < 20; ++i) {
        const int t = 3 * i;
        LOADA(t + 2, A2); ISSUE(t + 2, 2); vmwait<40>(); COMP(0, A0);
        LOADA(t + 3, A0); ISSUE(t + 3, 0); vmwait<40>(); COMP(1, A1);
        LOADA(t + 4, A1); ISSUE(t + 4, 1); vmwait<40>(); COMP(2, A2);
    }
    LOADA(62, A2); ISSUE(62, 2); vmwait<40>(); COMP(0, A0);
    LOADA(63, A0); ISSUE(63, 0); vmwait<40>(); COMP(1, A1);
    vmwait<20>(); COMP(2, A2);
    vmwait<0>();  COMP(0, A0);

    // ---- epilogue: LDS repack -> 16B coalesced hc stores (Bsh dead) ----
    short* S = (short*)Bsh;                  // [64][72] shorts, 9216 B
    #pragma unroll
    for (int nf = 0; nf < 4; ++nf)
        #pragma unroll
        for (int fm = 0; fm < 4; ++fm)
            #pragma unroll
            for (int r = 0; r < 4; ++r) {
                const int s = fm * 16 + g16 * 4 + r;
                const float g = accg[nf][fm][r];
                const float u = accu[nf][fm][r];
                const float hv = (g / (1.f + __expf(-g))) * u;
                S[s * 72 + nf * 16 + fl] = f2bf(hv);
            }
    LGKM0();
    short* myrow = hc + (size_t)e * SMAX * FFD + (size_t)lane * FFD + f0;
    #pragma unroll
    for (int j = 0; j < 8; ++j)
        *(short8*)(myrow + j * 8) = *(const short8*)(S + lane * 72 + j * 8);
}

// ---------------- Down: 3-deep NT-DMA pipeline -> partial[slotid][d] (no atomics) -------
// grid (DH/64=32, NE); block 64. LDS: 24KB.
__global__ __launch_bounds__(64) void moe_down(
    const short* __restrict__ hc, const float* __restrict__ wdp,
    const int* __restrict__ cnt, const int* __restrict__ tok_list,
    const float* __restrict__ w_list, float* __restrict__ partial)
{
    __shared__ __align__(16) float Bsh[3 * 2048];

    const int e = blockIdx.y;
    int n = cnt[e]; if (n > SMAX) n = SMAX;
    if (n == 0) return;

    const int lane = threadIdx.x;
    const int fl = lane & 15;
    const int g16 = lane >> 4;
    const int koff = g16 * 8;
    const int d0 = blockIdx.x * 64;
    const int lrow = lane >> 4;
    const int lcol = (lane & 15) * 4;

    const short* hce = hc + (size_t)e * SMAX * FFD;
    const float* wds = wdp + (size_t)e * FFD * DH + d0;

    f32x4 acc[4][4] = {};   // [nf][fm]
    short8 A0[4], A1[4], A2[4];

    auto ISSUE = [&](int t, int buf) {       // 8 glds (NT)
        const int kk = t * 32;
        float* bd = &Bsh[buf * 2048];
        #pragma unroll
        for (int g = 0; g < 8; ++g) {
            const size_t ro = (size_t)(kk + g * 4 + lrow) * DH + lcol;
            glds16nt(wds + ro, bd + g * 256);
        }
    };
    auto LOADA = [&](int t, short8 (&a)[4]) {
        const int kk = t * 32 + koff;
        #pragma unroll
        for (int fm = 0; fm < 4; ++fm)
            a[fm] = *(const short8*)(hce + (size_t)(fm * 16 + fl) * FFD + kk);
    };
    auto COMP = [&](int buf, const short8 (&a)[4]) {
        const float* bp = &Bsh[buf * 2048 + koff * 64 + fl];
        #pragma unroll
        for (int nf = 0; nf < 4; ++nf) {
            short8 bf;
            #pragma unroll
            for (int j = 0; j < 8; ++j) bf[j] = f2bf(bp[nf * 16 + j * 64]);
            #pragma unroll
            for (int fm = 0; fm < 4; ++fm)
                acc[nf][fm] = __builtin_amdgcn_mfma_f32_16x16x32_bf16(a[fm], bf, acc[nf][fm], 0, 0, 0);
        }
    };

    LOADA(0, A0); ISSUE(0, 0);
    LOADA(1, A1); ISSUE(1, 1);
    for (int i = 0; i < 6; ++i) {
        const int t = 3 * i;
        LOADA(t + 2, A2); ISSUE(t + 2, 2); vmwait<24>(); COMP(0, A0);
        LOADA(t + 3, A0); ISSUE(t + 3, 0); vmwait<24>(); COMP(1, A1);
        LOADA(t + 4, A1); ISSUE(t + 4, 1); vmwait<24>(); COMP(2, A2);
    }
    LOADA(20, A2); ISSUE(20, 2); vmwait<24>(); COMP(0, A0);
    LOADA(21, A0); ISSUE(21, 0); vmwait<24>(); COMP(1, A1);
    LOADA(22, A1); ISSUE(22, 1); vmwait<24>(); COMP(2, A2);
    LOADA(23, A2); ISSUE(23, 2); vmwait<24>(); COMP(0, A0);
    vmwait<12>(); COMP(1, A1);
    vmwait<0>();  COMP(2, A2);

    // ---- epilogue: LDS repack -> coalesced partial[slotid][d0..d0+63] stores ----
    float* P = (float*)Bsh;                  // [64][68] floats, 17408 B
    #pragma unroll
    for (int nf = 0; nf < 4; ++nf)
        #pragma unroll
        for (int fm = 0; fm < 4; ++fm)
            #pragma unroll
            for (int r = 0; r < 4; ++r) {
                const int s = fm * 16 + g16 * 4 + r;
                P[s * 68 + nf * 16 + fl] = acc[nf][fm][r];
            }
    LGKM0();
    if (lane < n) {
        const int slotid = tok_list[e * CAP + lane];
        const float wt = w_list[e * CAP + lane];
        float* prow = partial + (size_t)slotid * DH + d0;
        #pragma unroll
        for (int j = 0; j < 16; ++j) {
            float4 v = *(const float4*)(P + lane * 68 + j * 4);
            v.x *= wt; v.y *= wt; v.z *= wt; v.w *= wt;
            *(float4*)(prow + j * 4) = v;
        }
    }
}

// ---------------- Reduce: out[t][d] = sum_k partial[t*8+k][d] ----------------
// grid 1024; block 256 (512*512 float4s)
__global__ __launch_bounds__(256) void moe_reduce(
    const float4* __restrict__ partial, float4* __restrict__ out)
{
    const int i = blockIdx.x * 256 + threadIdx.x;
    const int t = i >> 9;
    const int d4 = i & 511;
    const float4* p = partial + (size_t)t * 8 * 512 + d4;
    float4 s = p[0];
    #pragma unroll
    for (int k = 1; k < 8; ++k) {
        const float4 v = p[(size_t)k * 512];
        s.x += v.x; s.y += v.y; s.z += v.z; s.w += v.w;
    }
    out[i] = s;
}

extern "C" void kernel_launch(void* const* d_in, const int* in_sizes, int n_in,
                              void* d_out, int out_size, void* d_ws, size_t ws_size,
                              hipStream_t stream) {
    const float* x   = (const float*)d_in[0];
    const float* wg  = (const float*)d_in[1];
    const float* wgp = (const float*)d_in[2];
    const float* wup = (const float*)d_in[3];
    const float* wdp = (const float*)d_in[4];
    float* out = (float*)d_out;

    char* ws = (char*)d_ws;
    int*   cnt      = (int*)ws;                              // 512 B
    int*   tok_list = (int*)(ws + 1024);                     // 256 KB
    float* w_list   = (float*)(ws + 1024 + NE * CAP * 4);    // 256 KB
    // region A (32 MiB): xgb lives gather..gateup; partial lives down..reduce (disjoint)
    short* xgb      = (short*)(ws + (1 << 20));
    float* partial  = (float*)(ws + (1 << 20));
    short* hc       = (short*)(ws + (1 << 20) + (size_t)NE * SMAX * DH * 2);  // +32MiB, 12 MiB

    moe_init<<<1, 128, 0, stream>>>(cnt);
    moe_router<<<TT, 128, 0, stream>>>(x, wg, cnt, tok_list, w_list);
    moe_gather<<<dim3(NE, 8), 256, 0, stream>>>(x, cnt, tok_list, xgb);
    moe_gateup<<<dim3(FFD / 64, NE), 64, 0, stream>>>(xgb, wgp, wup, hc);
    moe_down<<<dim3(DH / 64, NE), 64, 0, stream>>>(hc, wdp, cnt, tok_list, w_list, partial);
    moe_reduce<<<1024, 256, 0, stream>>>((const float4*)partial, (float4*)out);
}